// Round 7
// baseline (519.233 us; speedup 1.0000x reference)
//
#include <hip/hip_runtime.h>
#include <hip/hip_bf16.h>
#include <math.h>

#define TPB 256
#define BSHIFT 8                 // 256 nodes per bucket
#define BRANGE (1 << BSHIFT)     // == TPB (bucket_place relies on this)
#define CHUNK 8192               // edges per partition block
#define MAXB 512                 // max buckets (N <= 131072)

// ---------------- Threefry2x32 (exact JAX semantics) ----------------
__host__ __device__ inline void tf2x32(unsigned ks0, unsigned ks1,
                                       unsigned x0, unsigned x1,
                                       unsigned& o0, unsigned& o1) {
  const unsigned ks2 = ks0 ^ ks1 ^ 0x1BD11BDAu;
  unsigned v0 = x0 + ks0, v1 = x1 + ks1;
#define TF_RND(r) { v0 += v1; v1 = (v1 << (r)) | (v1 >> (32 - (r))); v1 ^= v0; }
  TF_RND(13) TF_RND(15) TF_RND(26) TF_RND(6)
  v0 += ks1; v1 += ks2 + 1u;
  TF_RND(17) TF_RND(29) TF_RND(16) TF_RND(24)
  v0 += ks2; v1 += ks0 + 2u;
  TF_RND(13) TF_RND(15) TF_RND(26) TF_RND(6)
  v0 += ks0; v1 += ks1 + 3u;
  TF_RND(17) TF_RND(29) TF_RND(16) TF_RND(24)
  v0 += ks1; v1 += ks2 + 4u;
  TF_RND(13) TF_RND(15) TF_RND(26) TF_RND(6)
  v0 += ks2; v1 += ks0 + 5u;
#undef TF_RND
  o0 = v0; o1 = v1;
}

__device__ __forceinline__ unsigned bits32(unsigned k0, unsigned k1, unsigned idx) {
  unsigned o0, o1;
  tf2x32(k0, k1, 0u, idx, o0, o1);
  return o0 ^ o1;
}

__device__ __forceinline__ float bits_to_u(unsigned bits) {
  float f = __uint_as_float((bits >> 9) | 0x3f800000u) - 1.0f;
  return (f > 0.0f) ? f : 1.17549435e-38f;
}

// exact path: fp64 logs rounded to fp32 at each stage (matches ref staging)
__device__ __forceinline__ float gumbel_exact(unsigned k0, unsigned k1, unsigned idx) {
  float u = bits_to_u(bits32(k0, k1, idx));
  float w = (float)(-log((double)u));
  return (float)(-log((double)w));
}

// fast path: fp32 logs (error ~1e-6 abs; used only when argmax gap is large)
__device__ __forceinline__ float gumbel_fast(unsigned k0, unsigned k1, unsigned idx) {
  float u = bits_to_u(bits32(k0, k1, idx));
  float w = -logf(u);
  return -logf(w);
}

// ---- counting-sort partition: hist -> colscan -> bucketscan -> place ----
// hist fused with the (independent) layer-1 matmul: blocks [0,nblk) do the edge
// histogram, blocks [nblk, nblk+mmblk) compute x@W1 (128->16, j-tiled fp64).
__global__ void hist_mm_kernel(const int* __restrict__ dst, int* __restrict__ histT,
                               int E, int nblk, int nbuckets,
                               const float* __restrict__ A, const float* __restrict__ W,
                               float* __restrict__ out, int N) {
  __shared__ int hist[MAXB];
  if ((int)blockIdx.x < nblk) {
    for (int i = threadIdx.x; i < nbuckets; i += TPB) hist[i] = 0;
    __syncthreads();
    int beg = blockIdx.x * CHUNK;
    int end = min(beg + CHUNK, E);
    for (int e = beg + threadIdx.x; e < end; e += TPB)
      atomicAdd(&hist[dst[e] >> BSHIFT], 1);
    __syncthreads();
    for (int i = threadIdx.x; i < nbuckets; i += TPB)
      histT[(size_t)i * nblk + blockIdx.x] = hist[i];
  } else {
    // matmul <K=128, J=16, LDO=16, TJ=4>
    int t = ((int)blockIdx.x - nblk) * TPB + threadIdx.x;
    int n = t / 4, jb = t % 4;
    if (n >= N) return;
    const float* a = A + (size_t)n * 128;
    const int j0 = jb * 4;
    double a0 = 0.0, a1 = 0.0, a2 = 0.0, a3 = 0.0;
    for (int k = 0; k < 128; k += 4) {
      float4 av = *(const float4*)&a[k];
      float4 w0 = *(const float4*)&W[(k + 0) * 16 + j0];
      float4 w1 = *(const float4*)&W[(k + 1) * 16 + j0];
      float4 w2 = *(const float4*)&W[(k + 2) * 16 + j0];
      float4 w3 = *(const float4*)&W[(k + 3) * 16 + j0];
      a0 += (double)av.x * (double)w0.x; a1 += (double)av.x * (double)w0.y;
      a2 += (double)av.x * (double)w0.z; a3 += (double)av.x * (double)w0.w;
      a0 += (double)av.y * (double)w1.x; a1 += (double)av.y * (double)w1.y;
      a2 += (double)av.y * (double)w1.z; a3 += (double)av.y * (double)w1.w;
      a0 += (double)av.z * (double)w2.x; a1 += (double)av.z * (double)w2.y;
      a2 += (double)av.z * (double)w2.z; a3 += (double)av.z * (double)w2.w;
      a0 += (double)av.w * (double)w3.x; a1 += (double)av.w * (double)w3.y;
      a2 += (double)av.w * (double)w3.z; a3 += (double)av.w * (double)w3.w;
    }
    float4 o;
    o.x = (float)a0; o.y = (float)a1; o.z = (float)a2; o.w = (float)a3;
    *(float4*)&out[(size_t)n * 16 + j0] = o;
  }
}

__global__ void colscan_kernel(int* __restrict__ histT, int* __restrict__ btot, int nblk) {
  __shared__ int sh[MAXB];
  int b = blockIdx.x;
  int t = threadIdx.x;
  sh[t] = (t < nblk) ? histT[(size_t)b * nblk + t] : 0;
  __syncthreads();
  for (int ofs = 1; ofs < MAXB; ofs <<= 1) {
    int v = (t >= ofs) ? sh[t - ofs] : 0;
    __syncthreads();
    sh[t] += v;
    __syncthreads();
  }
  if (t < nblk) histT[(size_t)b * nblk + t] = (t == 0) ? 0 : sh[t - 1];
  if (t == MAXB - 1) btot[b] = sh[MAXB - 1];
}

__global__ void bucketscan_kernel(const int* __restrict__ btot, int* __restrict__ bbase,
                                  int nbuckets, int E) {
  __shared__ int sh[MAXB];
  int t = threadIdx.x;
  sh[t] = (t < nbuckets) ? btot[t] : 0;
  __syncthreads();
  for (int ofs = 1; ofs < MAXB; ofs <<= 1) {
    int v = (t >= ofs) ? sh[t - ofs] : 0;
    __syncthreads();
    sh[t] += v;
    __syncthreads();
  }
  if (t < nbuckets) bbase[t] = (t == 0) ? 0 : sh[t - 1];
  if (t == 0) bbase[nbuckets] = E;
}

__global__ void place_kernel(const int* __restrict__ src, const int* __restrict__ dst,
                             const int* __restrict__ histT, const int* __restrict__ bbase,
                             unsigned* __restrict__ packed, int E, int nblk, int nbuckets) {
  __shared__ int cur[MAXB];
  for (int i = threadIdx.x; i < nbuckets; i += TPB)
    cur[i] = histT[(size_t)i * nblk + blockIdx.x] + bbase[i];
  __syncthreads();
  int beg = blockIdx.x * CHUNK;
  int end = min(beg + CHUNK, E);
  for (int e = beg + threadIdx.x; e < end; e += TPB) {
    int s = src[e], d = dst[e];
    int b = d >> BSHIFT;
    int pos = atomicAdd(&cur[b], 1);        // LDS atomic only
    packed[pos] = (unsigned)s | ((unsigned)(d & (BRANGE - 1)) << 20);
  }
}

__global__ void bucket_place_kernel(const int* __restrict__ bbase,
                                    const unsigned* __restrict__ packed,
                                    int* __restrict__ csr_src, int* __restrict__ rowptr,
                                    float* __restrict__ dinv, float* __restrict__ dinv2,
                                    int N, int nbuckets) {
  __shared__ int cnt[BRANGE];
  __shared__ int sh[BRANGE];
  __shared__ int cur[BRANGE];
  int b = blockIdx.x;
  int base = b << BSHIFT;
  int range_n = min(BRANGE, N - base);
  int t = threadIdx.x;           // TPB == BRANGE
  cnt[t] = 0;
  __syncthreads();
  int beg = bbase[b], end = bbase[b + 1];
  for (int e = beg + t; e < end; e += TPB)
    atomicAdd(&cnt[packed[e] >> 20], 1);
  __syncthreads();
  sh[t] = cnt[t];
  __syncthreads();
  for (int ofs = 1; ofs < BRANGE; ofs <<= 1) {
    int v = (t >= ofs) ? sh[t - ofs] : 0;
    __syncthreads();
    sh[t] += v;
    __syncthreads();
  }
  int excl = (t == 0) ? 0 : sh[t - 1];
  cur[t] = beg + excl;
  if (t < range_n) {
    rowptr[base + t] = beg + excl;
    float d = (float)(cnt[t] + 1);
    float di = 1.0f / sqrtf(d);          // identical expression to reference path
    dinv[base + t] = di;
    dinv2[base + t] = di * di;
  }
  if (b == nbuckets - 1 && t == 0) rowptr[N] = end;
  __syncthreads();
  for (int e = beg + t; e < end; e += TPB) {
    unsigned p = packed[e];
    int dstoff = (int)(p >> 20);
    int s = (int)(p & 0xFFFFFu);
    int pos = atomicAdd(&cur[dstoff], 1);
    csr_src[pos] = s;
  }
}

// ---------------- dense ops (fp64 accumulate, fp32 materialize) ----------------
// j-tiled matmul: TJ threads per node, each owning 4 adjacent outputs with 4
// INDEPENDENT fp64 accumulator chains (k ascending per output -> bit-identical
// to the scalar kernel). LDO = output row stride.
template <int K, int J, int LDO, int TJ>
__global__ void matmul_tile_kernel(const float* __restrict__ A, const float* __restrict__ W,
                                   float* __restrict__ out, int N) {
  static_assert(J == TJ * 4, "each thread owns 4 outputs");
  static_assert(K % 4 == 0, "K must be multiple of 4");
  int t = blockIdx.x * blockDim.x + threadIdx.x;
  int n = t / TJ, jb = t % TJ;
  if (n >= N) return;
  const float* a = A + (size_t)n * K;
  const int j0 = jb * 4;
  double a0 = 0.0, a1 = 0.0, a2 = 0.0, a3 = 0.0;
  for (int k = 0; k < K; k += 4) {
    float4 av = *(const float4*)&a[k];
    float4 w0 = *(const float4*)&W[(k + 0) * J + j0];
    float4 w1 = *(const float4*)&W[(k + 1) * J + j0];
    float4 w2 = *(const float4*)&W[(k + 2) * J + j0];
    float4 w3 = *(const float4*)&W[(k + 3) * J + j0];
    a0 += (double)av.x * (double)w0.x; a1 += (double)av.x * (double)w0.y;
    a2 += (double)av.x * (double)w0.z; a3 += (double)av.x * (double)w0.w;
    a0 += (double)av.y * (double)w1.x; a1 += (double)av.y * (double)w1.y;
    a2 += (double)av.y * (double)w1.z; a3 += (double)av.y * (double)w1.w;
    a0 += (double)av.z * (double)w2.x; a1 += (double)av.z * (double)w2.y;
    a2 += (double)av.z * (double)w2.z; a3 += (double)av.z * (double)w2.w;
    a0 += (double)av.w * (double)w3.x; a1 += (double)av.w * (double)w3.y;
    a2 += (double)av.w * (double)w3.z; a3 += (double)av.w * (double)w3.w;
  }
  float4 o;
  o.x = (float)a0; o.y = (float)a1; o.z = (float)a2; o.w = (float)a3;
  *(float4*)&out[(size_t)n * LDO + j0] = o;
}

// -------- layer-1 gather (J=16, 1 feat/lane) fused with mm2 (16->24) --------
// Round-2 gather geometry (8-deep batch). After the aggregation, lane j holds
// h1[n,j] = (float)acc + b1[j]; the 16-lane group then computes h1@W2 in the
// epilogue via __shfl (ascending k, fp64, identical fp32 inputs -> bit-equal
// to the standalone matmul_tile). W2 loaded as float2 (adjacent columns serve
// both output chains). Output written 32-padded (24 active).
__global__ void gather1_mm2_kernel(const int* __restrict__ rowptr,
                                   const int* __restrict__ csr_src,
                                   const float* __restrict__ dinv,
                                   const float* __restrict__ h,
                                   const float* __restrict__ dinv2,
                                   const float* __restrict__ b,
                                   const float* __restrict__ W2,
                                   float* __restrict__ out, int N) {
  constexpr int J = 16;
  int t = blockIdx.x * blockDim.x + threadIdx.x;
  int n = t / J, j = t % J;
  if (n >= N) return;
  int beg = rowptr[n], end = rowptr[n + 1];
  float dn = dinv[n];
  double acc = 0.0;
  for (int i = beg; i < end; i += J) {
    int m = end - i; if (m > J) m = J;
    int idx = i + j; if (idx >= end) idx = end - 1;
    int   sj = csr_src[idx];
    float wj = dinv[sj];
    int k = 0;
    for (; k + 8 <= m; k += 8) {
      int s0 = __shfl(sj, k + 0, J), s1 = __shfl(sj, k + 1, J);
      int s2 = __shfl(sj, k + 2, J), s3 = __shfl(sj, k + 3, J);
      int s4 = __shfl(sj, k + 4, J), s5 = __shfl(sj, k + 5, J);
      int s6 = __shfl(sj, k + 6, J), s7 = __shfl(sj, k + 7, J);
      float w0 = __shfl(wj, k + 0, J) * dn, w1 = __shfl(wj, k + 1, J) * dn;
      float w2 = __shfl(wj, k + 2, J) * dn, w3 = __shfl(wj, k + 3, J) * dn;
      float w4 = __shfl(wj, k + 4, J) * dn, w5 = __shfl(wj, k + 5, J) * dn;
      float w6 = __shfl(wj, k + 6, J) * dn, w7 = __shfl(wj, k + 7, J) * dn;
      float g0 = h[(size_t)s0 * J + j], g1 = h[(size_t)s1 * J + j];
      float g2 = h[(size_t)s2 * J + j], g3 = h[(size_t)s3 * J + j];
      float g4 = h[(size_t)s4 * J + j], g5 = h[(size_t)s5 * J + j];
      float g6 = h[(size_t)s6 * J + j], g7 = h[(size_t)s7 * J + j];
      acc += (double)g0 * (double)w0;
      acc += (double)g1 * (double)w1;
      acc += (double)g2 * (double)w2;
      acc += (double)g3 * (double)w3;
      acc += (double)g4 * (double)w4;
      acc += (double)g5 * (double)w5;
      acc += (double)g6 * (double)w6;
      acc += (double)g7 * (double)w7;
    }
    for (; k < m; ++k) {
      int   s = __shfl(sj, k, J);
      float w = __shfl(wj, k, J) * dn;
      acc += (double)h[(size_t)s * J + j] * (double)w;
    }
  }
  acc += (double)h[(size_t)n * J + j] * (double)dinv2[n];
  float hv = (float)acc + b[j];          // h1[n, j]

  // ---- mm2 epilogue: out[n, 2j..2j+1] = sum_k h1[n,k] * W2[k, 2j..2j+1] ----
  int j2 = (j < 12) ? j : 11;            // clamp keeps shfl convergent
  double m0 = 0.0, m1 = 0.0;
#pragma unroll
  for (int k = 0; k < 16; ++k) {
    float hk = __shfl(hv, k, J);
    float2 wv = *(const float2*)&W2[k * 24 + 2 * j2];
    m0 += (double)hk * (double)wv.x;
    m1 += (double)hk * (double)wv.y;
  }
  if (j < 12) {
    float2 o;
    o.x = (float)m0; o.y = (float)m1;
    *(float2*)&out[(size_t)n * 32 + 2 * j] = o;
  }
}

// ------- generic gather (float2/lane), round-2 geometry: compact JA write ----
template <int JA, int W, int LDH>
__global__ void gather_shfl2_kernel(const int* __restrict__ rowptr,
                                    const int* __restrict__ csr_src,
                                    const float* __restrict__ dinv,
                                    const float* __restrict__ h,
                                    const float* __restrict__ dinv2,
                                    const float* __restrict__ b,
                                    float* __restrict__ out, int N) {
  int t = blockIdx.x * blockDim.x + threadIdx.x;
  int n = t / W, j = t % W;
  if (n >= N) return;
  const int NJ = JA / 2;                 // active lanes per node
  int jj = (j < NJ) ? j : (NJ - 1);      // clamp keeps all lanes convergent
  int beg = rowptr[n], end = rowptr[n + 1];
  float dn = dinv[n];
  double acc0 = 0.0, acc1 = 0.0;
  for (int i = beg; i < end; i += W) {
    int m = end - i; if (m > W) m = W;
    int idx = i + j; if (idx >= end) idx = end - 1;
    int   sj = csr_src[idx];
    float wj = dinv[sj];
    int k = 0;
    for (; k + 8 <= m; k += 8) {
      int s0 = __shfl(sj, k + 0, W), s1 = __shfl(sj, k + 1, W);
      int s2 = __shfl(sj, k + 2, W), s3 = __shfl(sj, k + 3, W);
      int s4 = __shfl(sj, k + 4, W), s5 = __shfl(sj, k + 5, W);
      int s6 = __shfl(sj, k + 6, W), s7 = __shfl(sj, k + 7, W);
      float w0 = __shfl(wj, k + 0, W) * dn, w1 = __shfl(wj, k + 1, W) * dn;
      float w2 = __shfl(wj, k + 2, W) * dn, w3 = __shfl(wj, k + 3, W) * dn;
      float w4 = __shfl(wj, k + 4, W) * dn, w5 = __shfl(wj, k + 5, W) * dn;
      float w6 = __shfl(wj, k + 6, W) * dn, w7 = __shfl(wj, k + 7, W) * dn;
      float2 g0 = *(const float2*)&h[(size_t)s0 * LDH + 2 * jj];
      float2 g1 = *(const float2*)&h[(size_t)s1 * LDH + 2 * jj];
      float2 g2 = *(const float2*)&h[(size_t)s2 * LDH + 2 * jj];
      float2 g3 = *(const float2*)&h[(size_t)s3 * LDH + 2 * jj];
      float2 g4 = *(const float2*)&h[(size_t)s4 * LDH + 2 * jj];
      float2 g5 = *(const float2*)&h[(size_t)s5 * LDH + 2 * jj];
      float2 g6 = *(const float2*)&h[(size_t)s6 * LDH + 2 * jj];
      float2 g7 = *(const float2*)&h[(size_t)s7 * LDH + 2 * jj];
      acc0 += (double)g0.x * (double)w0; acc1 += (double)g0.y * (double)w0;
      acc0 += (double)g1.x * (double)w1; acc1 += (double)g1.y * (double)w1;
      acc0 += (double)g2.x * (double)w2; acc1 += (double)g2.y * (double)w2;
      acc0 += (double)g3.x * (double)w3; acc1 += (double)g3.y * (double)w3;
      acc0 += (double)g4.x * (double)w4; acc1 += (double)g4.y * (double)w4;
      acc0 += (double)g5.x * (double)w5; acc1 += (double)g5.y * (double)w5;
      acc0 += (double)g6.x * (double)w6; acc1 += (double)g6.y * (double)w6;
      acc0 += (double)g7.x * (double)w7; acc1 += (double)g7.y * (double)w7;
    }
    for (; k < m; ++k) {
      int   s = __shfl(sj, k, W);
      float w = __shfl(wj, k, W) * dn;
      float2 g = *(const float2*)&h[(size_t)s * LDH + 2 * jj];
      acc0 += (double)g.x * (double)w;
      acc1 += (double)g.y * (double)w;
    }
  }
  {
    float2 gs = *(const float2*)&h[(size_t)n * LDH + 2 * jj];
    double d2 = (double)dinv2[n];
    acc0 += (double)gs.x * d2;
    acc1 += (double)gs.y * d2;
  }
  if (j < NJ) {
    float2 o;
    o.x = (float)acc0 + b[2 * j];
    o.y = (float)acc1 + b[2 * j + 1];
    *(float2*)&out[(size_t)n * JA + 2 * j] = o;
  }
}

// ---------------- heads (phase 1: hidden layers, round-2 tiled form) ----------
__global__ void hid_start_kernel(const float* __restrict__ h,
                                 const float* __restrict__ Ws1, const float* __restrict__ bs1,
                                 float* __restrict__ hid, int N) {
  int t = blockIdx.x * blockDim.x + threadIdx.x;
  int n = t / 4, jb = t % 4;          // J=16 -> TJ=4
  if (n >= N) return;
  const float* hr = h + (size_t)n * 32;
  const int j0 = jb * 4;
  double a0 = 0.0, a1 = 0.0, a2 = 0.0, a3 = 0.0;
#pragma unroll
  for (int k = 0; k < 32; k += 4) {
    float4 av = *(const float4*)&hr[k];
    float4 w0 = *(const float4*)&Ws1[(k + 0) * 16 + j0];
    float4 w1 = *(const float4*)&Ws1[(k + 1) * 16 + j0];
    float4 w2 = *(const float4*)&Ws1[(k + 2) * 16 + j0];
    float4 w3 = *(const float4*)&Ws1[(k + 3) * 16 + j0];
    a0 += (double)av.x * (double)w0.x; a1 += (double)av.x * (double)w0.y;
    a2 += (double)av.x * (double)w0.z; a3 += (double)av.x * (double)w0.w;
    a0 += (double)av.y * (double)w1.x; a1 += (double)av.y * (double)w1.y;
    a2 += (double)av.y * (double)w1.z; a3 += (double)av.y * (double)w1.w;
    a0 += (double)av.z * (double)w2.x; a1 += (double)av.z * (double)w2.y;
    a2 += (double)av.z * (double)w2.z; a3 += (double)av.z * (double)w2.w;
    a0 += (double)av.w * (double)w3.x; a1 += (double)av.w * (double)w3.y;
    a2 += (double)av.w * (double)w3.z; a3 += (double)av.w * (double)w3.w;
  }
  float4 o;
  o.x = fminf(fmaxf((float)a0 + bs1[j0 + 0], 0.0f), 6.0f);
  o.y = fminf(fmaxf((float)a1 + bs1[j0 + 1], 0.0f), 6.0f);
  o.z = fminf(fmaxf((float)a2 + bs1[j0 + 2], 0.0f), 6.0f);
  o.w = fminf(fmaxf((float)a3 + bs1[j0 + 3], 0.0f), 6.0f);
  *(float4*)&hid[(size_t)n * 16 + j0] = o;
}

__global__ void hid_end_kernel(const float* __restrict__ h, const int* __restrict__ start,
                               const float* __restrict__ We1, const float* __restrict__ be1,
                               float* __restrict__ hid, int N) {
  int t = blockIdx.x * blockDim.x + threadIdx.x;
  int r = t / 6, jb = t % 6;          // J=24 -> TJ=6
  if (r >= 2 * N) return;
  int row = (r < N) ? r : start[r - N];
  const float* hr = h + (size_t)row * 32;
  const int j0 = jb * 4;
  double a0 = 0.0, a1 = 0.0, a2 = 0.0, a3 = 0.0;
#pragma unroll
  for (int k = 0; k < 32; k += 4) {
    float4 av = *(const float4*)&hr[k];
    float4 w0 = *(const float4*)&We1[(k + 0) * 24 + j0];
    float4 w1 = *(const float4*)&We1[(k + 1) * 24 + j0];
    float4 w2 = *(const float4*)&We1[(k + 2) * 24 + j0];
    float4 w3 = *(const float4*)&We1[(k + 3) * 24 + j0];
    a0 += (double)av.x * (double)w0.x; a1 += (double)av.x * (double)w0.y;
    a2 += (double)av.x * (double)w0.z; a3 += (double)av.x * (double)w0.w;
    a0 += (double)av.y * (double)w1.x; a1 += (double)av.y * (double)w1.y;
    a2 += (double)av.y * (double)w1.z; a3 += (double)av.y * (double)w1.w;
    a0 += (double)av.z * (double)w2.x; a1 += (double)av.z * (double)w2.y;
    a2 += (double)av.z * (double)w2.z; a3 += (double)av.z * (double)w2.w;
    a0 += (double)av.w * (double)w3.x; a1 += (double)av.w * (double)w3.y;
    a2 += (double)av.w * (double)w3.z; a3 += (double)av.w * (double)w3.w;
  }
  float4 o;
  o.x = fminf(fmaxf((float)a0 + be1[j0 + 0], 0.0f), 6.0f);
  o.y = fminf(fmaxf((float)a1 + be1[j0 + 1], 0.0f), 6.0f);
  o.z = fminf(fmaxf((float)a2 + be1[j0 + 2], 0.0f), 6.0f);
  o.w = fminf(fmaxf((float)a3 + be1[j0 + 3], 0.0f), 6.0f);
  *(float4*)&hid[(size_t)r * 24 + j0] = o;
}

// ------------- heads (phase 2: fast fp32 logits+gumbel, exact fp64 fallback) ----
// hid row loads vectorized to float4 (quad-wise, fmaf/add order unchanged ->
// bit-identical; rows are 16B-aligned: 16*4=64B, 24*4=96B strides).
template <int K>
__global__ void pick_kernel(const float* __restrict__ hid,
                            const float* __restrict__ W2, const float* __restrict__ b2,
                            int* __restrict__ outw, int R, unsigned k0, unsigned k1) {
  static_assert(K % 4 == 0, "K must be multiple of 4");
  int t = blockIdx.x * blockDim.x + threadIdx.x;
  int r = t >> 5;            // row
  int c = t & 31;            // class
  if (r >= R) return;
  const float* hr = hid + (size_t)r * K;

  // ---- fast path: fp32 dot + fp32 gumbel ----
  float af = 0.0f;
#pragma unroll
  for (int q = 0; q < K; q += 4) {
    float4 v = *(const float4*)&hr[q];
    af = fmaf(v.x, W2[(q + 0) * 32 + c], af);
    af = fmaf(v.y, W2[(q + 1) * 32 + c], af);
    af = fmaf(v.z, W2[(q + 2) * 32 + c], af);
    af = fmaf(v.w, W2[(q + 3) * 32 + c], af);
  }
  float zf = af + b2[c] + gumbel_fast(k0, k1, (unsigned)(r * 32 + c));

  // butterfly top-2 (m1,i1 = max w/ lower-index tie-break; m2 = runner-up value)
  float m1 = zf; int i1 = c; float m2 = -INFINITY;
#pragma unroll
  for (int m = 16; m >= 1; m >>= 1) {
    float om1 = __shfl_xor(m1, m, 32);
    int   oi1 = __shfl_xor(i1, m, 32);
    float om2 = __shfl_xor(m2, m, 32);
    if (om1 > m1 || (om1 == m1 && oi1 < i1)) {
      m2 = fmaxf(m1, om2);
      m1 = om1; i1 = oi1;
    } else {
      m2 = fmaxf(m2, om1);
    }
  }

  if (m1 - m2 >= 1e-3f) {            // safe: fast argmax == exact argmax
    if (c == 0) outw[r] = i1;
    return;
  }

  // ---- exact fallback (rare): fp64 dot + fp64-log gumbel, original argmax ----
  double a = 0.0;
#pragma unroll
  for (int q = 0; q < K; q += 4) {
    float4 v = *(const float4*)&hr[q];
    a += (double)v.x * (double)W2[(q + 0) * 32 + c];
    a += (double)v.y * (double)W2[(q + 1) * 32 + c];
    a += (double)v.z * (double)W2[(q + 2) * 32 + c];
    a += (double)v.w * (double)W2[(q + 3) * 32 + c];
  }
  float logit = (float)a + b2[c];
  float z = logit + gumbel_exact(k0, k1, (unsigned)(r * 32 + c));
  int best = c;
#pragma unroll
  for (int m = 16; m >= 1; m >>= 1) {
    float oz = __shfl_xor(z, m, 32);
    int   ob = __shfl_xor(best, m, 32);
    if (oz > z || (oz == z && ob < best)) { z = oz; best = ob; }
  }
  if (c == 0) outw[r] = best;
}

// ---------------- launch ----------------
extern "C" void kernel_launch(void* const* d_in, const int* in_sizes, int n_in,
                              void* d_out, int out_size, void* d_ws, size_t ws_size,
                              hipStream_t stream) {
  const float* x   = (const float*)d_in[0];
  const int*   ei  = (const int*)d_in[1];     // [2, E] int32
  const float* W1  = (const float*)d_in[3];
  const float* b1  = (const float*)d_in[4];
  const float* W2  = (const float*)d_in[5];
  const float* b2  = (const float*)d_in[6];
  const float* W3  = (const float*)d_in[7];
  const float* b3  = (const float*)d_in[8];
  const float* Ws1 = (const float*)d_in[9];
  const float* bs1 = (const float*)d_in[10];
  const float* Ws2 = (const float*)d_in[11];
  const float* bs2 = (const float*)d_in[12];
  const float* We1 = (const float*)d_in[13];
  const float* be1 = (const float*)d_in[14];
  const float* We2 = (const float*)d_in[15];
  const float* be2 = (const float*)d_in[16];

  const int N = in_sizes[0] / 128;
  const int E = in_sizes[1] / 2;
  const int* srcv = ei;
  const int* dstv = ei + E;
  const int nbuckets = (N + BRANGE - 1) >> BSHIFT;
  const int nblk = (E + CHUNK - 1) / CHUNK;

  char* ws = (char*)d_ws;
  size_t off = 0;
  float*    hA      = (float*)(ws + off);    off += (size_t)N * 32 * 4;
  float*    hB      = (float*)(ws + off);    off += (size_t)N * 32 * 4;
  int*      csr_src = (int*)(ws + off);      off += (size_t)E * 4;
  unsigned* packed  = (unsigned*)(ws + off); off += (size_t)E * 4;
  float*    dinv    = (float*)(ws + off);    off += (size_t)N * 4;
  float*    dinv2   = (float*)(ws + off);    off += (size_t)N * 4;
  int*      rowptr  = (int*)(ws + off);      off += (size_t)(N + 1) * 4;
  int*      histT   = (int*)(ws + off);      off += (size_t)nbuckets * nblk * 4;
  int*      btot    = (int*)(ws + off);      off += (size_t)MAXB * 4;
  int*      bbase   = (int*)(ws + off);      off += (size_t)(MAXB + 1) * 4;
  // head-phase overlays (dead regions by then)
  float* hid_start = hB;               // N*16 fp32 fits in hB (dead after g3)
  float* hid_end   = (float*)csr_src;  // 2N*24*4 = 19.2MB fits in csr_src+packed

  unsigned k1a, k1b, k2a, k2b;
  tf2x32(0u, 42u, 0u, 0u, k1a, k1b);
  tf2x32(0u, 42u, 0u, 1u, k2a, k2b);

  // CSR build (hist fused with layer-1 matmul) -> colscan -> bucketscan ->
  // place -> bucket_place
  const int mmblk = (int)(((size_t)N * 4 + TPB - 1) / TPB);
  hist_mm_kernel<<<nblk + mmblk, TPB, 0, stream>>>(dstv, histT, E, nblk, nbuckets,
                                                   x, W1, hA, N);
  colscan_kernel<<<nbuckets, MAXB, 0, stream>>>(histT, btot, nblk);
  bucketscan_kernel<<<1, MAXB, 0, stream>>>(btot, bbase, nbuckets, E);
  place_kernel<<<nblk, TPB, 0, stream>>>(srcv, dstv, histT, bbase, packed, E, nblk, nbuckets);
  bucket_place_kernel<<<nbuckets, TPB, 0, stream>>>(bbase, packed, csr_src, rowptr,
                                                    dinv, dinv2, N, nbuckets);

  // Layer 1 gather + mm2: hA(16-wide) -> hB(32-padded, 24 active = h1@W2)
  gather1_mm2_kernel<<<((size_t)N * 16 + TPB - 1) / TPB, TPB, 0, stream>>>(
      rowptr, csr_src, dinv, hA, dinv2, b1, W2, hB, N);

  // Layer 2 gather: hB(32-padded) -> hA(compact 24 = h2, +b2)
  gather_shfl2_kernel<24, 16, 32><<<((size_t)N * 16 + TPB - 1) / TPB, TPB, 0, stream>>>(
      rowptr, csr_src, dinv, hB, dinv2, b2, hA, N);

  // mm3: hA(24) -> hB(32-wide = h2@W3)
  matmul_tile_kernel<24, 32, 32, 8><<<((size_t)N * 8 + TPB - 1) / TPB, TPB, 0, stream>>>(hA, W3, hB, N);

  // Layer 3 gather: hB(32) -> hA(32 = h3, +b3)
  gather_shfl2_kernel<32, 16, 32><<<((size_t)N * 16 + TPB - 1) / TPB, TPB, 0, stream>>>(
      rowptr, csr_src, dinv, hB, dinv2, b3, hA, N);

  int* outI = (int*)d_out;

  // Start head
  hid_start_kernel<<<((size_t)N * 4 + TPB - 1) / TPB, TPB, 0, stream>>>(hA, Ws1, bs1, hid_start, N);
  pick_kernel<16><<<((size_t)N * 32 + TPB - 1) / TPB, TPB, 0, stream>>>(
      hid_start, Ws2, bs2, outI, N, k1a, k1b);

  // End head
  hid_end_kernel<<<((size_t)2 * N * 6 + TPB - 1) / TPB, TPB, 0, stream>>>(hA, outI, We1, be1, hid_end, N);
  pick_kernel<24><<<((size_t)2 * N * 32 + TPB - 1) / TPB, TPB, 0, stream>>>(
      hid_end, We2, be2, outI + N, 2 * N, k2a, k2b);
}

// Round 8
// 509.101 us; speedup vs baseline: 1.0199x; 1.0199x over previous
//
#include <hip/hip_runtime.h>
#include <hip/hip_bf16.h>
#include <math.h>

#define TPB 256
#define BSHIFT 8                 // 256 nodes per bucket
#define BRANGE (1 << BSHIFT)     // == TPB (bucket_place relies on this)
#define CHUNK 8192               // edges per partition block
#define MAXB 512                 // max buckets (N <= 131072)

// ---------------- Threefry2x32 (exact JAX semantics) ----------------
__host__ __device__ inline void tf2x32(unsigned ks0, unsigned ks1,
                                       unsigned x0, unsigned x1,
                                       unsigned& o0, unsigned& o1) {
  const unsigned ks2 = ks0 ^ ks1 ^ 0x1BD11BDAu;
  unsigned v0 = x0 + ks0, v1 = x1 + ks1;
#define TF_RND(r) { v0 += v1; v1 = (v1 << (r)) | (v1 >> (32 - (r))); v1 ^= v0; }
  TF_RND(13) TF_RND(15) TF_RND(26) TF_RND(6)
  v0 += ks1; v1 += ks2 + 1u;
  TF_RND(17) TF_RND(29) TF_RND(16) TF_RND(24)
  v0 += ks2; v1 += ks0 + 2u;
  TF_RND(13) TF_RND(15) TF_RND(26) TF_RND(6)
  v0 += ks0; v1 += ks1 + 3u;
  TF_RND(17) TF_RND(29) TF_RND(16) TF_RND(24)
  v0 += ks1; v1 += ks2 + 4u;
  TF_RND(13) TF_RND(15) TF_RND(26) TF_RND(6)
  v0 += ks2; v1 += ks0 + 5u;
#undef TF_RND
  o0 = v0; o1 = v1;
}

__device__ __forceinline__ unsigned bits32(unsigned k0, unsigned k1, unsigned idx) {
  unsigned o0, o1;
  tf2x32(k0, k1, 0u, idx, o0, o1);
  return o0 ^ o1;
}

__device__ __forceinline__ float bits_to_u(unsigned bits) {
  float f = __uint_as_float((bits >> 9) | 0x3f800000u) - 1.0f;
  return (f > 0.0f) ? f : 1.17549435e-38f;
}

// exact path: fp64 logs rounded to fp32 at each stage (matches ref staging)
__device__ __forceinline__ float gumbel_exact(unsigned k0, unsigned k1, unsigned idx) {
  float u = bits_to_u(bits32(k0, k1, idx));
  float w = (float)(-log((double)u));
  return (float)(-log((double)w));
}

// fast path: fp32 logs (error ~1e-6 abs; used only when argmax gap is large)
__device__ __forceinline__ float gumbel_fast(unsigned k0, unsigned k1, unsigned idx) {
  float u = bits_to_u(bits32(k0, k1, idx));
  float w = -logf(u);
  return -logf(w);
}

// ---- counting-sort partition: hist -> colscan -> bucketscan -> place ----
// hist fused with the (independent) layer-1 matmul: blocks [0,nblk) do the edge
// histogram, blocks [nblk, nblk+mmblk) compute x@W1 (128->16, j-tiled fp64).
__global__ void hist_mm_kernel(const int* __restrict__ dst, int* __restrict__ histT,
                               int E, int nblk, int nbuckets,
                               const float* __restrict__ A, const float* __restrict__ W,
                               float* __restrict__ out, int N) {
  __shared__ int hist[MAXB];
  if ((int)blockIdx.x < nblk) {
    for (int i = threadIdx.x; i < nbuckets; i += TPB) hist[i] = 0;
    __syncthreads();
    int beg = blockIdx.x * CHUNK;
    int end = min(beg + CHUNK, E);
    for (int e = beg + threadIdx.x; e < end; e += TPB)
      atomicAdd(&hist[dst[e] >> BSHIFT], 1);
    __syncthreads();
    for (int i = threadIdx.x; i < nbuckets; i += TPB)
      histT[(size_t)i * nblk + blockIdx.x] = hist[i];
  } else {
    // matmul <K=128, J=16, LDO=16, TJ=4>
    int t = ((int)blockIdx.x - nblk) * TPB + threadIdx.x;
    int n = t / 4, jb = t % 4;
    if (n >= N) return;
    const float* a = A + (size_t)n * 128;
    const int j0 = jb * 4;
    double a0 = 0.0, a1 = 0.0, a2 = 0.0, a3 = 0.0;
    for (int k = 0; k < 128; k += 4) {
      float4 av = *(const float4*)&a[k];
      float4 w0 = *(const float4*)&W[(k + 0) * 16 + j0];
      float4 w1 = *(const float4*)&W[(k + 1) * 16 + j0];
      float4 w2 = *(const float4*)&W[(k + 2) * 16 + j0];
      float4 w3 = *(const float4*)&W[(k + 3) * 16 + j0];
      a0 += (double)av.x * (double)w0.x; a1 += (double)av.x * (double)w0.y;
      a2 += (double)av.x * (double)w0.z; a3 += (double)av.x * (double)w0.w;
      a0 += (double)av.y * (double)w1.x; a1 += (double)av.y * (double)w1.y;
      a2 += (double)av.y * (double)w1.z; a3 += (double)av.y * (double)w1.w;
      a0 += (double)av.z * (double)w2.x; a1 += (double)av.z * (double)w2.y;
      a2 += (double)av.z * (double)w2.z; a3 += (double)av.z * (double)w2.w;
      a0 += (double)av.w * (double)w3.x; a1 += (double)av.w * (double)w3.y;
      a2 += (double)av.w * (double)w3.z; a3 += (double)av.w * (double)w3.w;
    }
    float4 o;
    o.x = (float)a0; o.y = (float)a1; o.z = (float)a2; o.w = (float)a3;
    *(float4*)&out[(size_t)n * 16 + j0] = o;
  }
}

__global__ void colscan_kernel(int* __restrict__ histT, int* __restrict__ btot, int nblk) {
  __shared__ int sh[MAXB];
  int b = blockIdx.x;
  int t = threadIdx.x;
  sh[t] = (t < nblk) ? histT[(size_t)b * nblk + t] : 0;
  __syncthreads();
  for (int ofs = 1; ofs < MAXB; ofs <<= 1) {
    int v = (t >= ofs) ? sh[t - ofs] : 0;
    __syncthreads();
    sh[t] += v;
    __syncthreads();
  }
  if (t < nblk) histT[(size_t)b * nblk + t] = (t == 0) ? 0 : sh[t - 1];
  if (t == MAXB - 1) btot[b] = sh[MAXB - 1];
}

__global__ void bucketscan_kernel(const int* __restrict__ btot, int* __restrict__ bbase,
                                  int nbuckets, int E) {
  __shared__ int sh[MAXB];
  int t = threadIdx.x;
  sh[t] = (t < nbuckets) ? btot[t] : 0;
  __syncthreads();
  for (int ofs = 1; ofs < MAXB; ofs <<= 1) {
    int v = (t >= ofs) ? sh[t - ofs] : 0;
    __syncthreads();
    sh[t] += v;
    __syncthreads();
  }
  if (t < nbuckets) bbase[t] = (t == 0) ? 0 : sh[t - 1];
  if (t == 0) bbase[nbuckets] = E;
}

__global__ void place_kernel(const int* __restrict__ src, const int* __restrict__ dst,
                             const int* __restrict__ histT, const int* __restrict__ bbase,
                             unsigned* __restrict__ packed, int E, int nblk, int nbuckets) {
  __shared__ int cur[MAXB];
  for (int i = threadIdx.x; i < nbuckets; i += TPB)
    cur[i] = histT[(size_t)i * nblk + blockIdx.x] + bbase[i];
  __syncthreads();
  int beg = blockIdx.x * CHUNK;
  int end = min(beg + CHUNK, E);
  for (int e = beg + threadIdx.x; e < end; e += TPB) {
    int s = src[e], d = dst[e];
    int b = d >> BSHIFT;
    int pos = atomicAdd(&cur[b], 1);        // LDS atomic only
    packed[pos] = (unsigned)s | ((unsigned)(d & (BRANGE - 1)) << 20);
  }
}

__global__ void bucket_place_kernel(const int* __restrict__ bbase,
                                    const unsigned* __restrict__ packed,
                                    int* __restrict__ csr_src, int* __restrict__ rowptr,
                                    float* __restrict__ dinv, float* __restrict__ dinv2,
                                    int N, int nbuckets) {
  __shared__ int cnt[BRANGE];
  __shared__ int sh[BRANGE];
  __shared__ int cur[BRANGE];
  int b = blockIdx.x;
  int base = b << BSHIFT;
  int range_n = min(BRANGE, N - base);
  int t = threadIdx.x;           // TPB == BRANGE
  cnt[t] = 0;
  __syncthreads();
  int beg = bbase[b], end = bbase[b + 1];
  for (int e = beg + t; e < end; e += TPB)
    atomicAdd(&cnt[packed[e] >> 20], 1);
  __syncthreads();
  sh[t] = cnt[t];
  __syncthreads();
  for (int ofs = 1; ofs < BRANGE; ofs <<= 1) {
    int v = (t >= ofs) ? sh[t - ofs] : 0;
    __syncthreads();
    sh[t] += v;
    __syncthreads();
  }
  int excl = (t == 0) ? 0 : sh[t - 1];
  cur[t] = beg + excl;
  if (t < range_n) {
    rowptr[base + t] = beg + excl;
    float d = (float)(cnt[t] + 1);
    float di = 1.0f / sqrtf(d);          // identical expression to reference path
    dinv[base + t] = di;
    dinv2[base + t] = di * di;
  }
  if (b == nbuckets - 1 && t == 0) rowptr[N] = end;
  __syncthreads();
  for (int e = beg + t; e < end; e += TPB) {
    unsigned p = packed[e];
    int dstoff = (int)(p >> 20);
    int s = (int)(p & 0xFFFFFu);
    int pos = atomicAdd(&cur[dstoff], 1);
    csr_src[pos] = s;
  }
}

// -------- layer-1 gather (J=16, 1 feat/lane) fused with mm2 (16->24) --------
// Round-2 gather geometry (8-deep batch). After the aggregation, lane j holds
// h1[n,j] = (float)acc + b1[j]; the 16-lane group then computes h1@W2 in the
// epilogue via __shfl (ascending k, fp64, identical fp32 inputs -> bit-equal
// to the standalone matmul_tile). W2 loaded as float2 (adjacent columns serve
// both output chains). Output written 32-padded (24 active).
__global__ void gather1_mm2_kernel(const int* __restrict__ rowptr,
                                   const int* __restrict__ csr_src,
                                   const float* __restrict__ dinv,
                                   const float* __restrict__ h,
                                   const float* __restrict__ dinv2,
                                   const float* __restrict__ b,
                                   const float* __restrict__ W2,
                                   float* __restrict__ out, int N) {
  constexpr int J = 16;
  int t = blockIdx.x * blockDim.x + threadIdx.x;
  int n = t / J, j = t % J;
  if (n >= N) return;
  int beg = rowptr[n], end = rowptr[n + 1];
  float dn = dinv[n];
  double acc = 0.0;
  for (int i = beg; i < end; i += J) {
    int m = end - i; if (m > J) m = J;
    int idx = i + j; if (idx >= end) idx = end - 1;
    int   sj = csr_src[idx];
    float wj = dinv[sj];
    int k = 0;
    for (; k + 8 <= m; k += 8) {
      int s0 = __shfl(sj, k + 0, J), s1 = __shfl(sj, k + 1, J);
      int s2 = __shfl(sj, k + 2, J), s3 = __shfl(sj, k + 3, J);
      int s4 = __shfl(sj, k + 4, J), s5 = __shfl(sj, k + 5, J);
      int s6 = __shfl(sj, k + 6, J), s7 = __shfl(sj, k + 7, J);
      float w0 = __shfl(wj, k + 0, J) * dn, w1 = __shfl(wj, k + 1, J) * dn;
      float w2 = __shfl(wj, k + 2, J) * dn, w3 = __shfl(wj, k + 3, J) * dn;
      float w4 = __shfl(wj, k + 4, J) * dn, w5 = __shfl(wj, k + 5, J) * dn;
      float w6 = __shfl(wj, k + 6, J) * dn, w7 = __shfl(wj, k + 7, J) * dn;
      float g0 = h[(size_t)s0 * J + j], g1 = h[(size_t)s1 * J + j];
      float g2 = h[(size_t)s2 * J + j], g3 = h[(size_t)s3 * J + j];
      float g4 = h[(size_t)s4 * J + j], g5 = h[(size_t)s5 * J + j];
      float g6 = h[(size_t)s6 * J + j], g7 = h[(size_t)s7 * J + j];
      acc += (double)g0 * (double)w0;
      acc += (double)g1 * (double)w1;
      acc += (double)g2 * (double)w2;
      acc += (double)g3 * (double)w3;
      acc += (double)g4 * (double)w4;
      acc += (double)g5 * (double)w5;
      acc += (double)g6 * (double)w6;
      acc += (double)g7 * (double)w7;
    }
    for (; k < m; ++k) {
      int   s = __shfl(sj, k, J);
      float w = __shfl(wj, k, J) * dn;
      acc += (double)h[(size_t)s * J + j] * (double)w;
    }
  }
  acc += (double)h[(size_t)n * J + j] * (double)dinv2[n];
  float hv = (float)acc + b[j];          // h1[n, j]

  // ---- mm2 epilogue: out[n, 2j..2j+1] = sum_k h1[n,k] * W2[k, 2j..2j+1] ----
  int j2 = (j < 12) ? j : 11;            // clamp keeps shfl convergent
  double m0 = 0.0, m1 = 0.0;
#pragma unroll
  for (int k = 0; k < 16; ++k) {
    float hk = __shfl(hv, k, J);
    float2 wv = *(const float2*)&W2[k * 24 + 2 * j2];
    m0 += (double)hk * (double)wv.x;
    m1 += (double)hk * (double)wv.y;
  }
  if (j < 12) {
    float2 o;
    o.x = (float)m0; o.y = (float)m1;
    *(float2*)&out[(size_t)n * 32 + 2 * j] = o;
  }
}

// ---- layer-2 gather (24 feats, float2/lane) fused with mm3 (24->32) --------
// Round-2 gather geometry. Lane jj<12 ends with h2[n,2jj], h2[n,2jj+1]
// (= (float)acc + b2); epilogue computes h2@W3 via __shfl (ascending k, fp64,
// bit-equal to standalone matmul_tile). W3 loaded as float2 (adjacent columns
// 2j/2j+1 serve both output chains; 8B-aligned). All 16 lanes store 2 outputs.
__global__ void gather2_mm3_kernel(const int* __restrict__ rowptr,
                                   const int* __restrict__ csr_src,
                                   const float* __restrict__ dinv,
                                   const float* __restrict__ h,
                                   const float* __restrict__ dinv2,
                                   const float* __restrict__ b,
                                   const float* __restrict__ W3,
                                   float* __restrict__ out, int N) {
  constexpr int W = 16, LDH = 32;
  int t = blockIdx.x * blockDim.x + threadIdx.x;
  int n = t / W, j = t % W;
  if (n >= N) return;
  int jj = (j < 12) ? j : 11;            // clamp keeps all lanes convergent
  int beg = rowptr[n], end = rowptr[n + 1];
  float dn = dinv[n];
  double acc0 = 0.0, acc1 = 0.0;
  for (int i = beg; i < end; i += W) {
    int m = end - i; if (m > W) m = W;
    int idx = i + j; if (idx >= end) idx = end - 1;
    int   sj = csr_src[idx];
    float wj = dinv[sj];
    int k = 0;
    for (; k + 8 <= m; k += 8) {
      int s0 = __shfl(sj, k + 0, W), s1 = __shfl(sj, k + 1, W);
      int s2 = __shfl(sj, k + 2, W), s3 = __shfl(sj, k + 3, W);
      int s4 = __shfl(sj, k + 4, W), s5 = __shfl(sj, k + 5, W);
      int s6 = __shfl(sj, k + 6, W), s7 = __shfl(sj, k + 7, W);
      float w0 = __shfl(wj, k + 0, W) * dn, w1 = __shfl(wj, k + 1, W) * dn;
      float w2 = __shfl(wj, k + 2, W) * dn, w3 = __shfl(wj, k + 3, W) * dn;
      float w4 = __shfl(wj, k + 4, W) * dn, w5 = __shfl(wj, k + 5, W) * dn;
      float w6 = __shfl(wj, k + 6, W) * dn, w7 = __shfl(wj, k + 7, W) * dn;
      float2 g0 = *(const float2*)&h[(size_t)s0 * LDH + 2 * jj];
      float2 g1 = *(const float2*)&h[(size_t)s1 * LDH + 2 * jj];
      float2 g2 = *(const float2*)&h[(size_t)s2 * LDH + 2 * jj];
      float2 g3 = *(const float2*)&h[(size_t)s3 * LDH + 2 * jj];
      float2 g4 = *(const float2*)&h[(size_t)s4 * LDH + 2 * jj];
      float2 g5 = *(const float2*)&h[(size_t)s5 * LDH + 2 * jj];
      float2 g6 = *(const float2*)&h[(size_t)s6 * LDH + 2 * jj];
      float2 g7 = *(const float2*)&h[(size_t)s7 * LDH + 2 * jj];
      acc0 += (double)g0.x * (double)w0; acc1 += (double)g0.y * (double)w0;
      acc0 += (double)g1.x * (double)w1; acc1 += (double)g1.y * (double)w1;
      acc0 += (double)g2.x * (double)w2; acc1 += (double)g2.y * (double)w2;
      acc0 += (double)g3.x * (double)w3; acc1 += (double)g3.y * (double)w3;
      acc0 += (double)g4.x * (double)w4; acc1 += (double)g4.y * (double)w4;
      acc0 += (double)g5.x * (double)w5; acc1 += (double)g5.y * (double)w5;
      acc0 += (double)g6.x * (double)w6; acc1 += (double)g6.y * (double)w6;
      acc0 += (double)g7.x * (double)w7; acc1 += (double)g7.y * (double)w7;
    }
    for (; k < m; ++k) {
      int   s = __shfl(sj, k, W);
      float w = __shfl(wj, k, W) * dn;
      float2 g = *(const float2*)&h[(size_t)s * LDH + 2 * jj];
      acc0 += (double)g.x * (double)w;
      acc1 += (double)g.y * (double)w;
    }
  }
  {
    float2 gs = *(const float2*)&h[(size_t)n * LDH + 2 * jj];
    double d2 = (double)dinv2[n];
    acc0 += (double)gs.x * d2;
    acc1 += (double)gs.y * d2;
  }
  float h0 = (float)acc0 + b[2 * jj];        // h2[n, 2jj]
  float h1 = (float)acc1 + b[2 * jj + 1];    // h2[n, 2jj+1]

  // ---- mm3 epilogue: out[n, 2j..2j+1] = sum_{k=0}^{23} h2[n,k]*W3[k, ...] ----
  double m0 = 0.0, m1 = 0.0;
#pragma unroll
  for (int k = 0; k < 12; ++k) {
    float e0 = __shfl(h0, k, W);           // feat 2k
    float e1 = __shfl(h1, k, W);           // feat 2k+1
    float2 wa = *(const float2*)&W3[(2 * k) * 32 + 2 * j];
    float2 wb = *(const float2*)&W3[(2 * k + 1) * 32 + 2 * j];
    m0 += (double)e0 * (double)wa.x;
    m0 += (double)e1 * (double)wb.x;
    m1 += (double)e0 * (double)wa.y;
    m1 += (double)e1 * (double)wb.y;
  }
  float2 o;
  o.x = (float)m0; o.y = (float)m1;
  *(float2*)&out[(size_t)n * 32 + 2 * j] = o;
}

// ------- layer-3 gather (32 feats, float2/lane), round-2 geometry -----------
template <int JA, int W, int LDH>
__global__ void gather_shfl2_kernel(const int* __restrict__ rowptr,
                                    const int* __restrict__ csr_src,
                                    const float* __restrict__ dinv,
                                    const float* __restrict__ h,
                                    const float* __restrict__ dinv2,
                                    const float* __restrict__ b,
                                    float* __restrict__ out, int N) {
  int t = blockIdx.x * blockDim.x + threadIdx.x;
  int n = t / W, j = t % W;
  if (n >= N) return;
  const int NJ = JA / 2;                 // active lanes per node
  int jj = (j < NJ) ? j : (NJ - 1);      // clamp keeps all lanes convergent
  int beg = rowptr[n], end = rowptr[n + 1];
  float dn = dinv[n];
  double acc0 = 0.0, acc1 = 0.0;
  for (int i = beg; i < end; i += W) {
    int m = end - i; if (m > W) m = W;
    int idx = i + j; if (idx >= end) idx = end - 1;
    int   sj = csr_src[idx];
    float wj = dinv[sj];
    int k = 0;
    for (; k + 8 <= m; k += 8) {
      int s0 = __shfl(sj, k + 0, W), s1 = __shfl(sj, k + 1, W);
      int s2 = __shfl(sj, k + 2, W), s3 = __shfl(sj, k + 3, W);
      int s4 = __shfl(sj, k + 4, W), s5 = __shfl(sj, k + 5, W);
      int s6 = __shfl(sj, k + 6, W), s7 = __shfl(sj, k + 7, W);
      float w0 = __shfl(wj, k + 0, W) * dn, w1 = __shfl(wj, k + 1, W) * dn;
      float w2 = __shfl(wj, k + 2, W) * dn, w3 = __shfl(wj, k + 3, W) * dn;
      float w4 = __shfl(wj, k + 4, W) * dn, w5 = __shfl(wj, k + 5, W) * dn;
      float w6 = __shfl(wj, k + 6, W) * dn, w7 = __shfl(wj, k + 7, W) * dn;
      float2 g0 = *(const float2*)&h[(size_t)s0 * LDH + 2 * jj];
      float2 g1 = *(const float2*)&h[(size_t)s1 * LDH + 2 * jj];
      float2 g2 = *(const float2*)&h[(size_t)s2 * LDH + 2 * jj];
      float2 g3 = *(const float2*)&h[(size_t)s3 * LDH + 2 * jj];
      float2 g4 = *(const float2*)&h[(size_t)s4 * LDH + 2 * jj];
      float2 g5 = *(const float2*)&h[(size_t)s5 * LDH + 2 * jj];
      float2 g6 = *(const float2*)&h[(size_t)s6 * LDH + 2 * jj];
      float2 g7 = *(const float2*)&h[(size_t)s7 * LDH + 2 * jj];
      acc0 += (double)g0.x * (double)w0; acc1 += (double)g0.y * (double)w0;
      acc0 += (double)g1.x * (double)w1; acc1 += (double)g1.y * (double)w1;
      acc0 += (double)g2.x * (double)w2; acc1 += (double)g2.y * (double)w2;
      acc0 += (double)g3.x * (double)w3; acc1 += (double)g3.y * (double)w3;
      acc0 += (double)g4.x * (double)w4; acc1 += (double)g4.y * (double)w4;
      acc0 += (double)g5.x * (double)w5; acc1 += (double)g5.y * (double)w5;
      acc0 += (double)g6.x * (double)w6; acc1 += (double)g6.y * (double)w6;
      acc0 += (double)g7.x * (double)w7; acc1 += (double)g7.y * (double)w7;
    }
    for (; k < m; ++k) {
      int   s = __shfl(sj, k, W);
      float w = __shfl(wj, k, W) * dn;
      float2 g = *(const float2*)&h[(size_t)s * LDH + 2 * jj];
      acc0 += (double)g.x * (double)w;
      acc1 += (double)g.y * (double)w;
    }
  }
  {
    float2 gs = *(const float2*)&h[(size_t)n * LDH + 2 * jj];
    double d2 = (double)dinv2[n];
    acc0 += (double)gs.x * d2;
    acc1 += (double)gs.y * d2;
  }
  if (j < NJ) {
    float2 o;
    o.x = (float)acc0 + b[2 * j];
    o.y = (float)acc1 + b[2 * j + 1];
    *(float2*)&out[(size_t)n * JA + 2 * j] = o;
  }
}

// ---------------- heads (phase 1: hidden layers, round-2 tiled form) ----------
__global__ void hid_start_kernel(const float* __restrict__ h,
                                 const float* __restrict__ Ws1, const float* __restrict__ bs1,
                                 float* __restrict__ hid, int N) {
  int t = blockIdx.x * blockDim.x + threadIdx.x;
  int n = t / 4, jb = t % 4;          // J=16 -> TJ=4
  if (n >= N) return;
  const float* hr = h + (size_t)n * 32;
  const int j0 = jb * 4;
  double a0 = 0.0, a1 = 0.0, a2 = 0.0, a3 = 0.0;
#pragma unroll
  for (int k = 0; k < 32; k += 4) {
    float4 av = *(const float4*)&hr[k];
    float4 w0 = *(const float4*)&Ws1[(k + 0) * 16 + j0];
    float4 w1 = *(const float4*)&Ws1[(k + 1) * 16 + j0];
    float4 w2 = *(const float4*)&Ws1[(k + 2) * 16 + j0];
    float4 w3 = *(const float4*)&Ws1[(k + 3) * 16 + j0];
    a0 += (double)av.x * (double)w0.x; a1 += (double)av.x * (double)w0.y;
    a2 += (double)av.x * (double)w0.z; a3 += (double)av.x * (double)w0.w;
    a0 += (double)av.y * (double)w1.x; a1 += (double)av.y * (double)w1.y;
    a2 += (double)av.y * (double)w1.z; a3 += (double)av.y * (double)w1.w;
    a0 += (double)av.z * (double)w2.x; a1 += (double)av.z * (double)w2.y;
    a2 += (double)av.z * (double)w2.z; a3 += (double)av.z * (double)w2.w;
    a0 += (double)av.w * (double)w3.x; a1 += (double)av.w * (double)w3.y;
    a2 += (double)av.w * (double)w3.z; a3 += (double)av.w * (double)w3.w;
  }
  float4 o;
  o.x = fminf(fmaxf((float)a0 + bs1[j0 + 0], 0.0f), 6.0f);
  o.y = fminf(fmaxf((float)a1 + bs1[j0 + 1], 0.0f), 6.0f);
  o.z = fminf(fmaxf((float)a2 + bs1[j0 + 2], 0.0f), 6.0f);
  o.w = fminf(fmaxf((float)a3 + bs1[j0 + 3], 0.0f), 6.0f);
  *(float4*)&hid[(size_t)n * 16 + j0] = o;
}

__global__ void hid_end_kernel(const float* __restrict__ h, const int* __restrict__ start,
                               const float* __restrict__ We1, const float* __restrict__ be1,
                               float* __restrict__ hid, int N) {
  int t = blockIdx.x * blockDim.x + threadIdx.x;
  int r = t / 6, jb = t % 6;          // J=24 -> TJ=6
  if (r >= 2 * N) return;
  int row = (r < N) ? r : start[r - N];
  const float* hr = h + (size_t)row * 32;
  const int j0 = jb * 4;
  double a0 = 0.0, a1 = 0.0, a2 = 0.0, a3 = 0.0;
#pragma unroll
  for (int k = 0; k < 32; k += 4) {
    float4 av = *(const float4*)&hr[k];
    float4 w0 = *(const float4*)&We1[(k + 0) * 24 + j0];
    float4 w1 = *(const float4*)&We1[(k + 1) * 24 + j0];
    float4 w2 = *(const float4*)&We1[(k + 2) * 24 + j0];
    float4 w3 = *(const float4*)&We1[(k + 3) * 24 + j0];
    a0 += (double)av.x * (double)w0.x; a1 += (double)av.x * (double)w0.y;
    a2 += (double)av.x * (double)w0.z; a3 += (double)av.x * (double)w0.w;
    a0 += (double)av.y * (double)w1.x; a1 += (double)av.y * (double)w1.y;
    a2 += (double)av.y * (double)w1.z; a3 += (double)av.y * (double)w1.w;
    a0 += (double)av.z * (double)w2.x; a1 += (double)av.z * (double)w2.y;
    a2 += (double)av.z * (double)w2.z; a3 += (double)av.z * (double)w2.w;
    a0 += (double)av.w * (double)w3.x; a1 += (double)av.w * (double)w3.y;
    a2 += (double)av.w * (double)w3.z; a3 += (double)av.w * (double)w3.w;
  }
  float4 o;
  o.x = fminf(fmaxf((float)a0 + be1[j0 + 0], 0.0f), 6.0f);
  o.y = fminf(fmaxf((float)a1 + be1[j0 + 1], 0.0f), 6.0f);
  o.z = fminf(fmaxf((float)a2 + be1[j0 + 2], 0.0f), 6.0f);
  o.w = fminf(fmaxf((float)a3 + be1[j0 + 3], 0.0f), 6.0f);
  *(float4*)&hid[(size_t)r * 24 + j0] = o;
}

// ------------- heads (phase 2: fast fp32 logits+gumbel, exact fp64 fallback) ----
template <int K>
__global__ void pick_kernel(const float* __restrict__ hid,
                            const float* __restrict__ W2, const float* __restrict__ b2,
                            int* __restrict__ outw, int R, unsigned k0, unsigned k1) {
  int t = blockIdx.x * blockDim.x + threadIdx.x;
  int r = t >> 5;            // row
  int c = t & 31;            // class
  if (r >= R) return;
  const float* hr = hid + (size_t)r * K;

  // ---- fast path: fp32 dot + fp32 gumbel ----
  float af = 0.0f;
#pragma unroll
  for (int k = 0; k < K; ++k) af = fmaf(hr[k], W2[k * 32 + c], af);
  float zf = af + b2[c] + gumbel_fast(k0, k1, (unsigned)(r * 32 + c));

  // butterfly top-2 (m1,i1 = max w/ lower-index tie-break; m2 = runner-up value)
  float m1 = zf; int i1 = c; float m2 = -INFINITY;
#pragma unroll
  for (int m = 16; m >= 1; m >>= 1) {
    float om1 = __shfl_xor(m1, m, 32);
    int   oi1 = __shfl_xor(i1, m, 32);
    float om2 = __shfl_xor(m2, m, 32);
    if (om1 > m1 || (om1 == m1 && oi1 < i1)) {
      m2 = fmaxf(m1, om2);
      m1 = om1; i1 = oi1;
    } else {
      m2 = fmaxf(m2, om1);
    }
  }

  if (m1 - m2 >= 1e-3f) {            // safe: fast argmax == exact argmax
    if (c == 0) outw[r] = i1;
    return;
  }

  // ---- exact fallback (rare): fp64 dot + fp64-log gumbel, original argmax ----
  double a = 0.0;
#pragma unroll
  for (int k = 0; k < K; ++k) a += (double)hr[k] * (double)W2[k * 32 + c];
  float logit = (float)a + b2[c];
  float z = logit + gumbel_exact(k0, k1, (unsigned)(r * 32 + c));
  int best = c;
#pragma unroll
  for (int m = 16; m >= 1; m >>= 1) {
    float oz = __shfl_xor(z, m, 32);
    int   ob = __shfl_xor(best, m, 32);
    if (oz > z || (oz == z && ob < best)) { z = oz; best = ob; }
  }
  if (c == 0) outw[r] = best;
}

// ---------------- launch ----------------
extern "C" void kernel_launch(void* const* d_in, const int* in_sizes, int n_in,
                              void* d_out, int out_size, void* d_ws, size_t ws_size,
                              hipStream_t stream) {
  const float* x   = (const float*)d_in[0];
  const int*   ei  = (const int*)d_in[1];     // [2, E] int32
  const float* W1  = (const float*)d_in[3];
  const float* b1  = (const float*)d_in[4];
  const float* W2  = (const float*)d_in[5];
  const float* b2  = (const float*)d_in[6];
  const float* W3  = (const float*)d_in[7];
  const float* b3  = (const float*)d_in[8];
  const float* Ws1 = (const float*)d_in[9];
  const float* bs1 = (const float*)d_in[10];
  const float* Ws2 = (const float*)d_in[11];
  const float* bs2 = (const float*)d_in[12];
  const float* We1 = (const float*)d_in[13];
  const float* be1 = (const float*)d_in[14];
  const float* We2 = (const float*)d_in[15];
  const float* be2 = (const float*)d_in[16];

  const int N = in_sizes[0] / 128;
  const int E = in_sizes[1] / 2;
  const int* srcv = ei;
  const int* dstv = ei + E;
  const int nbuckets = (N + BRANGE - 1) >> BSHIFT;
  const int nblk = (E + CHUNK - 1) / CHUNK;

  char* ws = (char*)d_ws;
  size_t off = 0;
  float*    hA      = (float*)(ws + off);    off += (size_t)N * 32 * 4;
  float*    hB      = (float*)(ws + off);    off += (size_t)N * 32 * 4;
  int*      csr_src = (int*)(ws + off);      off += (size_t)E * 4;
  unsigned* packed  = (unsigned*)(ws + off); off += (size_t)E * 4;
  float*    dinv    = (float*)(ws + off);    off += (size_t)N * 4;
  float*    dinv2   = (float*)(ws + off);    off += (size_t)N * 4;
  int*      rowptr  = (int*)(ws + off);      off += (size_t)(N + 1) * 4;
  int*      histT   = (int*)(ws + off);      off += (size_t)nbuckets * nblk * 4;
  int*      btot    = (int*)(ws + off);      off += (size_t)MAXB * 4;
  int*      bbase   = (int*)(ws + off);      off += (size_t)(MAXB + 1) * 4;
  // head-phase overlays (dead regions by then)
  float* hid_start = hA;               // N*16 fp32 fits in hA (N*32), dead after g3
  float* hid_end   = (float*)csr_src;  // 2N*24*4 = 19.2MB fits in csr_src+packed

  unsigned k1a, k1b, k2a, k2b;
  tf2x32(0u, 42u, 0u, 0u, k1a, k1b);
  tf2x32(0u, 42u, 0u, 1u, k2a, k2b);

  // CSR build (hist fused with layer-1 matmul) -> colscan -> bucketscan ->
  // place -> bucket_place
  const int mmblk = (int)(((size_t)N * 4 + TPB - 1) / TPB);
  hist_mm_kernel<<<nblk + mmblk, TPB, 0, stream>>>(dstv, histT, E, nblk, nbuckets,
                                                   x, W1, hA, N);
  colscan_kernel<<<nbuckets, MAXB, 0, stream>>>(histT, btot, nblk);
  bucketscan_kernel<<<1, MAXB, 0, stream>>>(btot, bbase, nbuckets, E);
  place_kernel<<<nblk, TPB, 0, stream>>>(srcv, dstv, histT, bbase, packed, E, nblk, nbuckets);
  bucket_place_kernel<<<nbuckets, TPB, 0, stream>>>(bbase, packed, csr_src, rowptr,
                                                    dinv, dinv2, N, nbuckets);

  // Layer 1 gather + mm2: hA(16-wide) -> hB(32-padded, 24 active)
  gather1_mm2_kernel<<<((size_t)N * 16 + TPB - 1) / TPB, TPB, 0, stream>>>(
      rowptr, csr_src, dinv, hA, dinv2, b1, W2, hB, N);

  // Layer 2 gather + mm3: hB -> hA(32-wide)
  gather2_mm3_kernel<<<((size_t)N * 16 + TPB - 1) / TPB, TPB, 0, stream>>>(
      rowptr, csr_src, dinv, hB, dinv2, b2, W3, hA, N);

  // Layer 3 gather: hA -> hB(32-wide)
  gather_shfl2_kernel<32, 16, 32><<<((size_t)N * 16 + TPB - 1) / TPB, TPB, 0, stream>>>(
      rowptr, csr_src, dinv, hA, dinv2, b3, hB, N);

  int* outI = (int*)d_out;

  // Start head
  hid_start_kernel<<<((size_t)N * 4 + TPB - 1) / TPB, TPB, 0, stream>>>(hB, Ws1, bs1, hid_start, N);
  pick_kernel<16><<<((size_t)N * 32 + TPB - 1) / TPB, TPB, 0, stream>>>(
      hid_start, Ws2, bs2, outI, N, k1a, k1b);

  // End head
  hid_end_kernel<<<((size_t)2 * N * 6 + TPB - 1) / TPB, TPB, 0, stream>>>(hB, outI, We1, be1, hid_end, N);
  pick_kernel<24><<<((size_t)2 * N * 32 + TPB - 1) / TPB, TPB, 0, stream>>>(
      hid_end, We2, be2, outI + N, 2 * N, k2a, k2b);
}